// Round 17
// baseline (1057.645 us; speedup 1.0000x reference)
//
#include <hip/hip_runtime.h>
#include <hip/hip_bf16.h>
#include <math.h>

#define BB 4
#define QTOT 5376
#define DMM 256
#define NHEADS 8
#define HDIM 32
#define NPTS 4
#define NLVLS 3
#define BQ (BB*QTOT)   // 21504
#define NOA 288        // packed off(192)+aw(96)

typedef short bf16x8 __attribute__((ext_vector_type(8)));
typedef unsigned short u16x8 __attribute__((ext_vector_type(8)));
typedef float f32x4  __attribute__((ext_vector_type(4)));

__device__ __forceinline__ unsigned short f2b(float f) {
  unsigned int u = __float_as_uint(f);
  unsigned int r = (u + 0x7FFFu + ((u >> 16) & 1u)) >> 16;   // RNE
  return (unsigned short)r;
}
__device__ __forceinline__ float b2f(unsigned short u) {
  return __uint_as_float(((unsigned int)u) << 16);
}
__device__ __forceinline__ ushort4 f2b4(float4 v) {
  ushort4 o; o.x = f2b(v.x); o.y = f2b(v.y); o.z = f2b(v.z); o.w = f2b(v.w);
  return o;
}

__device__ __forceinline__ void gload16(const void* g, void* l) {
  __builtin_amdgcn_global_load_lds(
      (const __attribute__((address_space(1))) void*)g,
      (__attribute__((address_space(3))) void*)l, 16, 0, 0);
}

// ---------------------------------------------------------------------------
// Transpose (B,C,H,W) -> (B, HW, C) slice of (B, QTOT, C), optional +embed[c]
// ---------------------------------------------------------------------------
__global__ __launch_bounds__(256) void transpose_in(
    const float* __restrict__ src, const float* __restrict__ emb,
    float* __restrict__ dst, int HW, int qstart)
{
  __shared__ float t[32][33];
  int hw0 = blockIdx.x * 32, c0 = blockIdx.y * 32, b = blockIdx.z;
  int tx = threadIdx.x, ty = threadIdx.y;
  const float* s = src + ((size_t)b * DMM + c0) * HW + hw0;
#pragma unroll
  for (int j = 0; j < 4; j++)
    t[ty * 4 + j][tx] = s[(size_t)(ty * 4 + j) * HW + tx];
  __syncthreads();
  float e = emb ? emb[c0 + tx] : 0.0f;
  float* d = dst + ((size_t)b * QTOT + qstart + hw0) * DMM + c0;
#pragma unroll
  for (int j = 0; j < 4; j++)
    d[(size_t)(ty * 4 + j) * DMM + tx] = t[tx][ty * 4 + j] + e;
}

// fp32 -> bf16 elementwise (vector of 4)
__global__ __launch_bounds__(256) void conv_b(
    const float* __restrict__ s, unsigned short* __restrict__ d, int n4)
{
  int i = blockIdx.x * 256 + threadIdx.x;
  if (i >= n4) return;
  ((ushort4*)d)[i] = f2b4(((const float4*)s)[i]);
}

// pack off_w/aw_w -> (6, 288, 256) bf16
__global__ __launch_bounds__(256) void pack_oa(
    const float* __restrict__ offw, const float* __restrict__ aww,
    unsigned short* __restrict__ dst)
{
  int i = blockIdx.x * 256 + threadIdx.x;          // group of 4 cols
  if (i >= 6 * NOA * 64) return;
  int c4 = i & 63;
  int row = (i >> 6) % NOA;
  int l = i / (NOA * 64);
  const float* src = (row < 192)
      ? offw + ((size_t)l * 192 + row) * 256
      : aww  + ((size_t)l * 96 + (row - 192)) * 256;
  float4 v = ((const float4*)src)[c4];
  ((ushort4*)dst)[i] = f2b4(v);
}

__global__ __launch_bounds__(256) void pack_oa_bias(
    const float* __restrict__ offb, const float* __restrict__ awb,
    float* __restrict__ dst)
{
  int i = blockIdx.x * 256 + threadIdx.x;
  if (i >= 6 * NOA) return;
  int row = i % NOA, l = i / NOA;
  dst[i] = (row < 192) ? offb[l * 192 + row] : awb[l * 96 + (row - 192)];
}

// xb = bf16(x), qb = bf16(x+pos), pos16 = bf16(pos)
__global__ __launch_bounds__(256) void prep(
    const float* __restrict__ x, const float* __restrict__ pos,
    unsigned short* __restrict__ xb, unsigned short* __restrict__ qb,
    unsigned short* __restrict__ pos16, int n4)
{
  int i = blockIdx.x * 256 + threadIdx.x;
  if (i >= n4) return;
  float4 a = ((const float4*)x)[i];
  float4 p = ((const float4*)pos)[i];
  ((ushort4*)xb)[i] = f2b4(a);
  ((ushort4*)pos16)[i] = f2b4(p);
  float4 q = make_float4(a.x + p.x, a.y + p.y, a.z + p.z, a.w + p.w);
  ((ushort4*)qb)[i] = f2b4(q);
}

// ---------------------------------------------------------------------------
// Core 128x128 MFMA tile body, double-buffered, swizzled chunks (r8-proven).
// ---------------------------------------------------------------------------
__device__ __forceinline__ void gemm_tile_body(
    const unsigned short* __restrict__ A, const unsigned short* __restrict__ W,
    int m0, int n0, int K,
    unsigned short (*As)[32], unsigned short (*Ws)[32], f32x4 acc[4][4])
{
  int tid = threadIdx.x;
  int wave = tid >> 6, lane = tid & 63;
  int lr = lane & 15;
  int lkr = ((lane >> 4) ^ (lane & 3)) * 8;        // swizzled read chunk
  int wrr = (wave >> 1) * 64;
  int wcc = (wave & 1) * 64;

  int srow = lane >> 2;
  int schunk = ((lane & 3) ^ (srow & 3)) * 8;      // swizzled source chunk
  const unsigned short* Ag = A + (size_t)(m0 + wave * 32 + srow) * K + schunk;
  const unsigned short* Wg = W + (size_t)(n0 + wave * 32 + srow) * K + schunk;

#define STAGE_BF(k0, buf)                                                      \
  { int bo = (buf) * 128 + wave * 32;                                          \
    gload16(Ag + (k0), &As[bo][0]);                                            \
    gload16(Ag + (size_t)16 * K + (k0), &As[bo + 16][0]);                      \
    gload16(Wg + (k0), &Ws[bo][0]);                                            \
    gload16(Wg + (size_t)16 * K + (k0), &Ws[bo + 16][0]); }

  STAGE_BF(0, 0);
  __syncthreads();
  int cur = 0;
  for (int k0 = 0; k0 < K; k0 += 32) {
    if (k0 + 32 < K) STAGE_BF(k0 + 32, cur ^ 1);
    int bo = cur * 128;
    bf16x8 af[4], bfv[4];
#pragma unroll
    for (int m = 0; m < 4; m++)
      af[m] = *(const bf16x8*)&As[bo + wrr + m * 16 + lr][lkr];
#pragma unroll
    for (int n = 0; n < 4; n++)
      bfv[n] = *(const bf16x8*)&Ws[bo + wcc + n * 16 + lr][lkr];
#pragma unroll
    for (int m = 0; m < 4; m++)
#pragma unroll
      for (int n = 0; n < 4; n++)
        acc[m][n] = __builtin_amdgcn_mfma_f32_16x16x32_bf16(af[m], bfv[n], acc[m][n], 0, 0, 0);
    __syncthreads();
    cur ^= 1;
  }
#undef STAGE_BF
}

__device__ __forceinline__ void gemm_epilogue(
    const float* __restrict__ bias, void* __restrict__ Cout,
    int m0, int n0, int N, int relu, int bfout, f32x4 acc[4][4])
{
  int tid = threadIdx.x;
  int wave = tid >> 6, lane = tid & 63;
  int lr = lane & 15;
  int wrr = (wave >> 1) * 64;
  int wcc = (wave & 1) * 64;
  float* C32 = (float*)Cout;
  unsigned short* C16 = (unsigned short*)Cout;
#pragma unroll
  for (int n = 0; n < 4; n++) {
    int col = n0 + wcc + n * 16 + lr;
    if (col >= N) continue;
    float bv = bias[col];
#pragma unroll
    for (int m = 0; m < 4; m++) {
      int row0 = m0 + wrr + m * 16 + (lane >> 4) * 4;
#pragma unroll
      for (int j = 0; j < 4; j++) {
        float v = acc[m][n][j] + bv;
        if (relu) v = fmaxf(v, 0.0f);
        if (bfout) C16[(size_t)(row0 + j) * N + col] = f2b(v);
        else       C32[(size_t)(row0 + j) * N + col] = v;
      }
    }
  }
}

// generic GEMM (used for ffn1)
__global__ __launch_bounds__(256) void gemm_bf(
    const unsigned short* __restrict__ A, const unsigned short* __restrict__ W,
    const float* __restrict__ bias, void* __restrict__ Cout,
    int M, int N, int K, int flags)
{
  __shared__ unsigned short As[256][32];
  __shared__ unsigned short Ws[256][32];
  f32x4 acc[4][4] = {};
  int m0 = blockIdx.x * 128, n0 = blockIdx.y * 128;
  gemm_tile_body(A, W, m0, n0, K, As, Ws, acc);
  gemm_epilogue(bias, Cout, m0, n0, N, flags & 1, flags & 2, acc);
}

// merged value-proj + off/aw-proj (both bf16 out). grid (M/128, 5).
__global__ __launch_bounds__(256) void gemm_valoa(
    const unsigned short* __restrict__ xb, const unsigned short* __restrict__ qb,
    const unsigned short* __restrict__ vW, const unsigned short* __restrict__ oaW,
    const float* __restrict__ vBias, const float* __restrict__ oaBias,
    unsigned short* __restrict__ valb16, unsigned short* __restrict__ offaw16)
{
  __shared__ unsigned short As[256][32];
  __shared__ unsigned short Ws[256][32];
  f32x4 acc[4][4] = {};
  int m0 = blockIdx.x * 128;
  int by = blockIdx.y;
  const int K = 256;
  if (by < 2) {
    int n0 = by * 128;
    gemm_tile_body(xb, vW, m0, n0, K, As, Ws, acc);
    gemm_epilogue(vBias, valb16, m0, n0, 256, 0, 2, acc);
  } else {
    int n0 = (by - 2) * 128;
    gemm_tile_body(qb, oaW, m0, n0, K, As, Ws, acc);
    gemm_epilogue(oaBias, offaw16, m0, n0, NOA, 0, 2, acc);
  }
}

// ---------------------------------------------------------------------------
// Fused GEMM (N=256) + bias + residual + LayerNorm.
// W streams DIRECTLY to registers (compiler-counted vmcnt, spans barriers);
// A reg-staged into a tiny 5 KB double-buffered LDS; per-step sync is a raw
// s_barrier + lgkmcnt(0) only — NO vmcnt(0) drain anywhere in the main loop.
// BM=32, 512 thr / 8 waves, wave owns cols [wave*32,+32), acc[2][2].
// ---------------------------------------------------------------------------
__global__ __launch_bounds__(512) void gemm_ln(
    const unsigned short* __restrict__ A, const unsigned short* __restrict__ W,
    const float* __restrict__ bias, const float* __restrict__ g,
    const float* __restrict__ beta, float* __restrict__ x,
    unsigned short* __restrict__ xb, const unsigned short* __restrict__ pos16,
    unsigned short* __restrict__ qb, int K)
{
  __shared__ unsigned short As[2][32][40];   // 5 KB; 80B row stride (16B-aligned)
  __shared__ float2 red[32 * 8];             // 2 KB LN reduction

  int m0 = blockIdx.x * 32;
  int tid = threadIdx.x;
  int wave = tid >> 6, lane = tid & 63;      // wave 0..7 owns cols [wave*32,+32)
  int lr = lane & 15;
  int p4 = lane >> 4;

  // A staging (waves 0,1): row = wave*16 + lane>>2, 16B chunk = lane&3
  bool stg = wave < 2;
  int srow = wave * 16 + (lane >> 2);
  int sch = (lane & 3) * 8;
  const unsigned short* Ag = A + (size_t)(m0 + srow) * K + sch;

  // W direct-register fragment pointers (two output-col frags per wave)
  const unsigned short* Wg0 = W + (size_t)(wave * 32 + lr) * K + p4 * 8;
  const unsigned short* Wg1 = W + (size_t)(wave * 32 + 16 + lr) * K + p4 * 8;

  f32x4 acc[2][2] = {};
  int nst = K >> 5;

  // prologue: stage A step0; preload W step0
  u16x8 a_nx = {};
  if (stg) a_nx = *(const u16x8*)(Ag);
  bf16x8 wn0 = *(const bf16x8*)(Wg0);
  bf16x8 wn1 = *(const bf16x8*)(Wg1);
  if (stg) *(u16x8*)&As[0][srow][sch] = a_nx;
  asm volatile("s_waitcnt lgkmcnt(0)" ::: "memory");
  __builtin_amdgcn_s_barrier();
  __builtin_amdgcn_sched_barrier(0);

  int cur = 0;
  for (int t = 0; t < nst; ++t) {
    bf16x8 wm0, wm1; u16x8 aa = {};
    if (t + 1 < nst) {
      if (stg) aa = *(const u16x8*)(Ag + (size_t)(t + 1) * 32);
      wm0 = *(const bf16x8*)(Wg0 + (size_t)(t + 1) * 32);
      wm1 = *(const bf16x8*)(Wg1 + (size_t)(t + 1) * 32);
    }
    bf16x8 af0 = *(const bf16x8*)&As[cur][lr][p4 * 8];
    bf16x8 af1 = *(const bf16x8*)&As[cur][16 + lr][p4 * 8];
    acc[0][0] = __builtin_amdgcn_mfma_f32_16x16x32_bf16(af0, wn0, acc[0][0], 0, 0, 0);
    acc[0][1] = __builtin_amdgcn_mfma_f32_16x16x32_bf16(af0, wn1, acc[0][1], 0, 0, 0);
    acc[1][0] = __builtin_amdgcn_mfma_f32_16x16x32_bf16(af1, wn0, acc[1][0], 0, 0, 0);
    acc[1][1] = __builtin_amdgcn_mfma_f32_16x16x32_bf16(af1, wn1, acc[1][1], 0, 0, 0);
    if (t + 1 < nst) {
      if (stg) *(u16x8*)&As[cur ^ 1][srow][sch] = aa;   // vmcnt counted at this dep
      wn0 = wm0; wn1 = wm1;
    }
    asm volatile("s_waitcnt lgkmcnt(0)" ::: "memory");  // ds ops only
    __builtin_amdgcn_s_barrier();
    __builtin_amdgcn_sched_barrier(0);
    cur ^= 1;
  }

  // v = gemm + bias + residual (f32)
#pragma unroll
  for (int n = 0; n < 2; n++) {
    int col = wave * 32 + n * 16 + lr;
    float bv = bias[col];
#pragma unroll
    for (int m = 0; m < 2; m++) {
      int grow = m0 + m * 16 + p4 * 4;
#pragma unroll
      for (int j = 0; j < 4; j++)
        acc[m][n][j] += bv + x[(size_t)(grow + j) * DMM + col];
    }
  }

  // per-row (sum, sumsq): 2 n-frags in-reg, 16 lanes shfl, 8 waves via LDS
#pragma unroll
  for (int m = 0; m < 2; m++) {
#pragma unroll
    for (int j = 0; j < 4; j++) {
      float s  = acc[m][0][j] + acc[m][1][j];
      float s2 = acc[m][0][j] * acc[m][0][j] + acc[m][1][j] * acc[m][1][j];
#pragma unroll
      for (int o = 1; o < 16; o <<= 1) {
        s  += __shfl_xor(s,  o, 64);
        s2 += __shfl_xor(s2, o, 64);
      }
      if (lr == 0)
        red[(m * 16 + p4 * 4 + j) * 8 + wave] = make_float2(s, s2);
    }
  }
  __syncthreads();

#pragma unroll
  for (int m = 0; m < 2; m++) {
#pragma unroll
    for (int j = 0; j < 4; j++) {
      int rl = m * 16 + p4 * 4 + j;
      float ts = 0.f, ts2 = 0.f;
#pragma unroll
      for (int wv = 0; wv < 8; wv++) {
        float2 r = red[rl * 8 + wv];
        ts += r.x; ts2 += r.y;
      }
      float mean = ts * (1.0f / DMM);
      float var  = ts2 * (1.0f / DMM) - mean * mean;
      float sc = rsqrtf(var + 1e-5f);
      int grow = m0 + rl;
#pragma unroll
      for (int n = 0; n < 2; n++) {
        int col = wave * 32 + n * 16 + lr;
        float o = (acc[m][n][j] - mean) * sc * g[col] + beta[col];
        size_t idx = (size_t)grow * DMM + col;
        x[idx]  = o;
        xb[idx] = f2b(o);
        if (qb) qb[idx] = f2b(o + b2f(pos16[idx]));
      }
    }
  }
}

// ---------------------------------------------------------------------------
// Deformable sampling. Block = 8 queries x 32 lanes (8 heads x 4 dgroups of 8ch).
// offaw16 is bf16 (B,QTOT,288): off [0..192), aw [192..288).
// ---------------------------------------------------------------------------
__global__ __launch_bounds__(256) void msda_sample(
    const unsigned short* __restrict__ value, const unsigned short* __restrict__ offaw16,
    unsigned short* __restrict__ attn16)
{
  __shared__ float saw[8][96];
  __shared__ float smx[64], sinv[64];
  __shared__ float swgt[768 * 4];   // [p][q][h] x 4 weights
  __shared__ int   sofs[768 * 4];   // [p][q][h] x 4 byte offsets

  int tid = threadIdx.x;
  int qi = tid >> 5, t32 = tid & 31;
  int h = t32 >> 2, dg = t32 & 3;
  int bq0 = blockIdx.x * 8;
  int bq = bq0 + qi;
  int b = bq / QTOT;

  for (int i = t32; i < 96; i += 32)
    saw[qi][i] = b2f(offaw16[(size_t)bq * NOA + 192 + i]);
  __syncthreads();

  if (tid < 64) {
    int q2 = tid >> 3, h2 = tid & 7;
    float mx = -1e30f;
#pragma unroll
    for (int t = 0; t < 12; t++) mx = fmaxf(mx, saw[q2][h2 * 12 + t]);
    float den = 0.f;
#pragma unroll
    for (int t = 0; t < 12; t++) den += __expf(saw[q2][h2 * 12 + t] - mx);
    smx[tid] = mx;
    sinv[tid] = 1.0f / den;
  }
  __syncthreads();

  // phase 2: point-set precompute (s = p*64 + q*8 + h)
  for (int s = tid; s < 768; s += 256) {
    int p = s >> 6;
    int qh = s & 63;
    int q2 = qh >> 3, h2 = qh & 7;
    int l = p >> 2;
    int Wl = 64 >> l;
    int st = (l == 0) ? 0 : ((l == 1) ? 4096 : 5120);

    int q = (bq0 + q2) % QTOT;
    int qq, Wq;
    if (q < 4096)      { qq = q;        Wq = 64; }
    else if (q < 5120) { qq = q - 4096; Wq = 32; }
    else               { qq = q - 5120; Wq = 16; }
    float refx = ((qq % Wq) + 0.5f) / Wq;
    float refy = ((qq / Wq) + 0.5f) / Wq;

    int oi = ((h2 * NLVLS + l) * NPTS + (p & 3)) * 2;
    ushort2 ob = *(const ushort2*)&offaw16[(size_t)(bq0 + q2) * NOA + oi];
    float offx = b2f(ob.x), offy = b2f(ob.y);
    float invW = 1.0f / (float)Wl;
    float xf = (refx + offx * invW) * Wl - 0.5f;
    float yf = (refy + offy * invW) * Wl - 0.5f;
    float x0f = floorf(xf), y0f = floorf(yf);
    float fx = xf - x0f, fy = yf - y0f;
    int x0 = (int)x0f, y0 = (int)y0f;

    float aw = __expf(saw[q2][h2 * 12 + p] - smx[qh]) * sinv[qh];
    float w00 = (1.f - fx) * (1.f - fy) * aw;
    float w10 = fx * (1.f - fy) * aw;
    float w01 = (1.f - fx) * fy * aw;
    float w11 = fx * fy * aw;

    bool xv0 = (x0 >= 0) & (x0 < Wl);
    bool xv1 = (x0 + 1 >= 0) & (x0 + 1 < Wl);
    bool yv0 = (y0 >= 0) & (y0 < Wl);
    bool yv1 = (y0 + 1 >= 0) & (y0 + 1 < Wl);

    int base = s * 4;
    swgt[base + 0] = (xv0 & yv0) ? w00 : 0.f;
    swgt[base + 1] = (xv1 & yv0) ? w10 : 0.f;
    swgt[base + 2] = (xv0 & yv1) ? w01 : 0.f;
    swgt[base + 3] = (xv1 & yv1) ? w11 : 0.f;
    sofs[base + 0] = (xv0 & yv0) ? (st + y0 * Wl + x0) * (DMM * 2) : 0;
    sofs[base + 1] = (xv1 & yv0) ? (st + y0 * Wl + x0 + 1) * (DMM * 2) : 0;
    sofs[base + 2] = (xv0 & yv1) ? (st + (y0 + 1) * Wl + x0) * (DMM * 2) : 0;
    sofs[base + 3] = (xv1 & yv1) ? (st + (y0 + 1) * Wl + x0 + 1) * (DMM * 2) : 0;
  }
  __syncthreads();

  // phase 3: gathers (8 channels per lane)
  float a8[8];
#pragma unroll
  for (int k = 0; k < 8; k++) a8[k] = 0.f;
  const char* vbase = (const char*)(value + (size_t)b * QTOT * DMM + h * HDIM + dg * 8);
#pragma unroll
  for (int p = 0; p < 12; p++) {
    int s3 = (p * 64 + qi * 8 + h) * 4;
    float4 w = *(const float4*)&swgt[s3];
    int4  of = *(const int4*)&sofs[s3];
    u16x8 g0 = *(const u16x8*)(vbase + of.x);
    u16x8 g1 = *(const u16x8*)(vbase + of.y);
    u16x8 g2 = *(const u16x8*)(vbase + of.z);
    u16x8 g3 = *(const u16x8*)(vbase + of.w);
#pragma unroll
    for (int k = 0; k < 8; k++)
      a8[k] += w.x * b2f((unsigned short)g0[k]) + w.y * b2f((unsigned short)g1[k])
             + w.z * b2f((unsigned short)g2[k]) + w.w * b2f((unsigned short)g3[k]);
  }
  u16x8 o;
#pragma unroll
  for (int k = 0; k < 8; k++) o[k] = f2b(a8[k]);
  *(u16x8*)(attn16 + (size_t)bq * DMM + h * HDIM + dg * 8) = o;
}

// ---------------------------------------------------------------------------
extern "C" void kernel_launch(void* const* d_in, const int* in_sizes, int n_in,
                              void* d_out, int out_size, void* d_ws, size_t ws_size,
                              hipStream_t stream)
{
  const float* src[3] = {(const float*)d_in[0], (const float*)d_in[1], (const float*)d_in[2]};
  const float* pin[3] = {(const float*)d_in[3], (const float*)d_in[4], (const float*)d_in[5]};
  const float* lvl_emb = (const float*)d_in[6];
  const float* off_w = (const float*)d_in[7];
  const float* off_b = (const float*)d_in[8];
  const float* aw_w  = (const float*)d_in[9];
  const float* aw_b  = (const float*)d_in[10];
  const float* val_w = (const float*)d_in[11];
  const float* val_b = (const float*)d_in[12];
  const float* out_w = (const float*)d_in[13];
  const float* out_b = (const float*)d_in[14];
  const float* ln1_g = (const float*)d_in[15];
  const float* ln1_b = (const float*)d_in[16];
  const float* ffn1_w = (const float*)d_in[17];
  const float* ffn1_b = (const float*)d_in[18];
  const float* ffn2_w = (const float*)d_in[19];
  const float* ffn2_b = (const float*)d_in[20];
  const float* ln2_g = (const float*)d_in[21];
  const float* ln2_b = (const float*)d_in[22];

  float* x = (float*)d_out;                                  // (B,QTOT,256) f32

  char* wsp = (char*)d_ws;
  unsigned short* offaw16 = (unsigned short*)wsp; wsp += (size_t)BQ * NOA * 2; // 12.4 MB
  unsigned short* valb16  = (unsigned short*)wsp; wsp += (size_t)BQ * 256 * 2; // 11 MB
  unsigned short* attnb   = (unsigned short*)wsp; wsp += (size_t)BQ * 256 * 2; // 11 MB
  unsigned short* hb = offaw16;  // aliased region; pad below so 44 MB fits
  wsp += (size_t)10 * 1024 * 1024;
  float* posb = (float*)wsp;  wsp += (size_t)BQ * 256 * 4;
  unsigned short* pos16 = (unsigned short*)wsp; wsp += (size_t)BQ * 256 * 2;
  unsigned short* xb = (unsigned short*)wsp; wsp += (size_t)BQ * 256 * 2;
  unsigned short* qb = (unsigned short*)wsp; wsp += (size_t)BQ * 256 * 2;

  unsigned short* vWb  = (unsigned short*)wsp; wsp += (size_t)6 * 256 * 256 * 2;
  unsigned short* oaWb = (unsigned short*)wsp; wsp += (size_t)6 * NOA * 256 * 2;
  unsigned short* uWb  = (unsigned short*)wsp; wsp += (size_t)6 * 256 * 256 * 2;
  unsigned short* f1Wb = (unsigned short*)wsp; wsp += (size_t)6 * 1024 * 256 * 2;
  unsigned short* f2Wb = (unsigned short*)wsp; wsp += (size_t)6 * 256 * 1024 * 2;
  float* oaBias = (float*)wsp; wsp += (size_t)6 * NOA * 4;
  wsp += 65536;   // slack for masked-N OOB staging reads

  conv_b<<<(6 * 65536 / 4 + 255) / 256, 256, 0, stream>>>(val_w, vWb, 6 * 65536 / 4);
  conv_b<<<(6 * 65536 / 4 + 255) / 256, 256, 0, stream>>>(out_w, uWb, 6 * 65536 / 4);
  conv_b<<<(6 * 262144 / 4 + 255) / 256, 256, 0, stream>>>(ffn1_w, f1Wb, 6 * 262144 / 4);
  conv_b<<<(6 * 262144 / 4 + 255) / 256, 256, 0, stream>>>(ffn2_w, f2Wb, 6 * 262144 / 4);
  pack_oa<<<(6 * NOA * 64 + 255) / 256, 256, 0, stream>>>(off_w, aw_w, oaWb);
  pack_oa_bias<<<(6 * NOA + 255) / 256, 256, 0, stream>>>(off_b, aw_b, oaBias);

  const int HWs[3] = {4096, 1024, 256};
  const int starts[3] = {0, 4096, 5120};
  for (int l = 0; l < 3; l++) {
    dim3 g(HWs[l] / 32, DMM / 32, BB), blk(32, 8);
    transpose_in<<<g, blk, 0, stream>>>(src[l], nullptr, x, HWs[l], starts[l]);
    transpose_in<<<g, blk, 0, stream>>>(pin[l], lvl_emb + l * 256, posb, HWs[l], starts[l]);
  }
  prep<<<(BQ * 256 / 4 + 255) / 256, 256, 0, stream>>>(x, posb, xb, qb, pos16, BQ * 256 / 4);

  for (int i = 0; i < 6; i++) {
    gemm_valoa<<<dim3(BQ / 128, 5), 256, 0, stream>>>(
        xb, qb, vWb + (size_t)i * 65536, oaWb + (size_t)i * NOA * 256,
        val_b + i * 256, oaBias + i * NOA, valb16, offaw16);
    msda_sample<<<BQ / 8, 256, 0, stream>>>(valb16, offaw16, attnb);
    gemm_ln<<<BQ / 32, 512, 0, stream>>>(attnb, uWb + (size_t)i * 65536,
        out_b + i * 256, ln1_g + i * 256, ln1_b + i * 256, x, xb,
        nullptr, nullptr, 256);
    gemm_bf<<<dim3(BQ / 128, 8), 256, 0, stream>>>(xb, f1Wb + (size_t)i * 262144,
        ffn1_b + i * 1024, hb, BQ, 1024, 256, 1 | 2);
    gemm_ln<<<BQ / 32, 512, 0, stream>>>(hb, f2Wb + (size_t)i * 262144,
        ffn2_b + i * 256, ln2_g + i * 256, ln2_b + i * 256, x, xb,
        pos16, qb, 1024);
  }
}

// Round 18
// 920.428 us; speedup vs baseline: 1.1491x; 1.1491x over previous
//
#include <hip/hip_runtime.h>
#include <hip/hip_bf16.h>
#include <math.h>

#define BB 4
#define QTOT 5376
#define DMM 256
#define NHEADS 8
#define HDIM 32
#define NPTS 4
#define NLVLS 3
#define BQ (BB*QTOT)   // 21504
#define NOA 288        // packed off(192)+aw(96)

typedef short bf16x8 __attribute__((ext_vector_type(8)));
typedef unsigned short u16x8 __attribute__((ext_vector_type(8)));
typedef float f32x4  __attribute__((ext_vector_type(4)));

__device__ __forceinline__ unsigned short f2b(float f) {
  unsigned int u = __float_as_uint(f);
  unsigned int r = (u + 0x7FFFu + ((u >> 16) & 1u)) >> 16;   // RNE
  return (unsigned short)r;
}
__device__ __forceinline__ float b2f(unsigned short u) {
  return __uint_as_float(((unsigned int)u) << 16);
}
__device__ __forceinline__ ushort4 f2b4(float4 v) {
  ushort4 o; o.x = f2b(v.x); o.y = f2b(v.y); o.z = f2b(v.z); o.w = f2b(v.w);
  return o;
}

__device__ __forceinline__ void gload16(const void* g, void* l) {
  __builtin_amdgcn_global_load_lds(
      (const __attribute__((address_space(1))) void*)g,
      (__attribute__((address_space(3))) void*)l, 16, 0, 0);
}

// ---------------------------------------------------------------------------
// Merged transpose: (B,C,H,W) src -> x (f32, B,QTOT,C); pos -> pos16 (bf16,
// +level_embed). grid (HW/32, C/32, B), block (32,8).
// ---------------------------------------------------------------------------
__global__ __launch_bounds__(256) void transpose2(
    const float* __restrict__ src, const float* __restrict__ pos,
    const float* __restrict__ emb, float* __restrict__ x,
    unsigned short* __restrict__ pos16, int HW, int qstart)
{
  __shared__ float ts[32][33];
  __shared__ float tp[32][33];
  int hw0 = blockIdx.x * 32, c0 = blockIdx.y * 32, b = blockIdx.z;
  int tx = threadIdx.x, ty = threadIdx.y;
  const float* s = src + ((size_t)b * DMM + c0) * HW + hw0;
  const float* p = pos + ((size_t)b * DMM + c0) * HW + hw0;
#pragma unroll
  for (int j = 0; j < 4; j++) {
    ts[ty * 4 + j][tx] = s[(size_t)(ty * 4 + j) * HW + tx];
    tp[ty * 4 + j][tx] = p[(size_t)(ty * 4 + j) * HW + tx];
  }
  __syncthreads();
  float e = emb[c0 + tx];
  size_t base = ((size_t)b * QTOT + qstart + hw0) * DMM + c0;
#pragma unroll
  for (int j = 0; j < 4; j++) {
    x[base + (size_t)(ty * 4 + j) * DMM + tx] = ts[tx][ty * 4 + j];
    pos16[base + (size_t)(ty * 4 + j) * DMM + tx] = f2b(tp[tx][ty * 4 + j] + e);
  }
}

// fp32 -> bf16 elementwise (vector of 4)
__global__ __launch_bounds__(256) void conv_b(
    const float* __restrict__ s, unsigned short* __restrict__ d, int n4)
{
  int i = blockIdx.x * 256 + threadIdx.x;
  if (i >= n4) return;
  ((ushort4*)d)[i] = f2b4(((const float4*)s)[i]);
}

// pack off_w/aw_w -> (6, 288, 256) bf16
__global__ __launch_bounds__(256) void pack_oa(
    const float* __restrict__ offw, const float* __restrict__ aww,
    unsigned short* __restrict__ dst)
{
  int i = blockIdx.x * 256 + threadIdx.x;          // group of 4 cols
  if (i >= 6 * NOA * 64) return;
  int c4 = i & 63;
  int row = (i >> 6) % NOA;
  int l = i / (NOA * 64);
  const float* src = (row < 192)
      ? offw + ((size_t)l * 192 + row) * 256
      : aww  + ((size_t)l * 96 + (row - 192)) * 256;
  float4 v = ((const float4*)src)[c4];
  ((ushort4*)dst)[i] = f2b4(v);
}

__global__ __launch_bounds__(256) void pack_oa_bias(
    const float* __restrict__ offb, const float* __restrict__ awb,
    float* __restrict__ dst)
{
  int i = blockIdx.x * 256 + threadIdx.x;
  if (i >= 6 * NOA) return;
  int row = i % NOA, l = i / NOA;
  dst[i] = (row < 192) ? offb[l * 192 + row] : awb[l * 96 + (row - 192)];
}

// xb = bf16(x), qb = bf16(x + pos16)
__global__ __launch_bounds__(256) void prep(
    const float* __restrict__ x, const unsigned short* __restrict__ pos16,
    unsigned short* __restrict__ xb, unsigned short* __restrict__ qb, int n4)
{
  int i = blockIdx.x * 256 + threadIdx.x;
  if (i >= n4) return;
  float4 a = ((const float4*)x)[i];
  ushort4 p = ((const ushort4*)pos16)[i];
  ((ushort4*)xb)[i] = f2b4(a);
  ushort4 q;
  q.x = f2b(a.x + b2f(p.x)); q.y = f2b(a.y + b2f(p.y));
  q.z = f2b(a.z + b2f(p.z)); q.w = f2b(a.w + b2f(p.w));
  ((ushort4*)qb)[i] = q;
}

// ---------------------------------------------------------------------------
// Core 128x128 MFMA tile body, double-buffered, swizzled chunks (r8-proven).
// ---------------------------------------------------------------------------
__device__ __forceinline__ void gemm_tile_body(
    const unsigned short* __restrict__ A, const unsigned short* __restrict__ W,
    int m0, int n0, int K,
    unsigned short (*As)[32], unsigned short (*Ws)[32], f32x4 acc[4][4])
{
  int tid = threadIdx.x;
  int wave = tid >> 6, lane = tid & 63;
  int lr = lane & 15;
  int lkr = ((lane >> 4) ^ (lane & 3)) * 8;        // swizzled read chunk
  int wrr = (wave >> 1) * 64;
  int wcc = (wave & 1) * 64;

  int srow = lane >> 2;
  int schunk = ((lane & 3) ^ (srow & 3)) * 8;      // swizzled source chunk
  const unsigned short* Ag = A + (size_t)(m0 + wave * 32 + srow) * K + schunk;
  const unsigned short* Wg = W + (size_t)(n0 + wave * 32 + srow) * K + schunk;

#define STAGE_BF(k0, buf)                                                      \
  { int bo = (buf) * 128 + wave * 32;                                          \
    gload16(Ag + (k0), &As[bo][0]);                                            \
    gload16(Ag + (size_t)16 * K + (k0), &As[bo + 16][0]);                      \
    gload16(Wg + (k0), &Ws[bo][0]);                                            \
    gload16(Wg + (size_t)16 * K + (k0), &Ws[bo + 16][0]); }

  STAGE_BF(0, 0);
  __syncthreads();
  int cur = 0;
  for (int k0 = 0; k0 < K; k0 += 32) {
    if (k0 + 32 < K) STAGE_BF(k0 + 32, cur ^ 1);
    int bo = cur * 128;
    bf16x8 af[4], bfv[4];
#pragma unroll
    for (int m = 0; m < 4; m++)
      af[m] = *(const bf16x8*)&As[bo + wrr + m * 16 + lr][lkr];
#pragma unroll
    for (int n = 0; n < 4; n++)
      bfv[n] = *(const bf16x8*)&Ws[bo + wcc + n * 16 + lr][lkr];
#pragma unroll
    for (int m = 0; m < 4; m++)
#pragma unroll
      for (int n = 0; n < 4; n++)
        acc[m][n] = __builtin_amdgcn_mfma_f32_16x16x32_bf16(af[m], bfv[n], acc[m][n], 0, 0, 0);
    __syncthreads();
    cur ^= 1;
  }
#undef STAGE_BF
}

__device__ __forceinline__ void gemm_epilogue(
    const float* __restrict__ bias, void* __restrict__ Cout,
    int m0, int n0, int N, int relu, int bfout, f32x4 acc[4][4])
{
  int tid = threadIdx.x;
  int wave = tid >> 6, lane = tid & 63;
  int lr = lane & 15;
  int wrr = (wave >> 1) * 64;
  int wcc = (wave & 1) * 64;
  float* C32 = (float*)Cout;
  unsigned short* C16 = (unsigned short*)Cout;
#pragma unroll
  for (int n = 0; n < 4; n++) {
    int col = n0 + wcc + n * 16 + lr;
    if (col >= N) continue;
    float bv = bias[col];
#pragma unroll
    for (int m = 0; m < 4; m++) {
      int row0 = m0 + wrr + m * 16 + (lane >> 4) * 4;
#pragma unroll
      for (int j = 0; j < 4; j++) {
        float v = acc[m][n][j] + bv;
        if (relu) v = fmaxf(v, 0.0f);
        if (bfout) C16[(size_t)(row0 + j) * N + col] = f2b(v);
        else       C32[(size_t)(row0 + j) * N + col] = v;
      }
    }
  }
}

// generic GEMM (used for ffn1)
__global__ __launch_bounds__(256) void gemm_bf(
    const unsigned short* __restrict__ A, const unsigned short* __restrict__ W,
    const float* __restrict__ bias, void* __restrict__ Cout,
    int M, int N, int K, int flags)
{
  __shared__ unsigned short As[256][32];
  __shared__ unsigned short Ws[256][32];
  f32x4 acc[4][4] = {};
  int m0 = blockIdx.x * 128, n0 = blockIdx.y * 128;
  gemm_tile_body(A, W, m0, n0, K, As, Ws, acc);
  gemm_epilogue(bias, Cout, m0, n0, N, flags & 1, flags & 2, acc);
}

// merged value-proj + off/aw-proj (both bf16 out). grid (M/128, 5).
__global__ __launch_bounds__(256) void gemm_valoa(
    const unsigned short* __restrict__ xb, const unsigned short* __restrict__ qb,
    const unsigned short* __restrict__ vW, const unsigned short* __restrict__ oaW,
    const float* __restrict__ vBias, const float* __restrict__ oaBias,
    unsigned short* __restrict__ valb16, unsigned short* __restrict__ offaw16)
{
  __shared__ unsigned short As[256][32];
  __shared__ unsigned short Ws[256][32];
  f32x4 acc[4][4] = {};
  int m0 = blockIdx.x * 128;
  int by = blockIdx.y;
  const int K = 256;
  if (by < 2) {
    int n0 = by * 128;
    gemm_tile_body(xb, vW, m0, n0, K, As, Ws, acc);
    gemm_epilogue(vBias, valb16, m0, n0, 256, 0, 2, acc);
  } else {
    int n0 = (by - 2) * 128;
    gemm_tile_body(qb, oaW, m0, n0, K, As, Ws, acc);
    gemm_epilogue(oaBias, offaw16, m0, n0, NOA, 0, 2, acc);
  }
}

// ---------------------------------------------------------------------------
// Fused GEMM (N=256) + bias + residual + LayerNorm (r12/r16-proven body).
// BM=32, 512 thr / 8 waves — each wave owns 32 cols (acc[2][2]).
// ---------------------------------------------------------------------------
__global__ __launch_bounds__(512) void gemm_ln(
    const unsigned short* __restrict__ A, const unsigned short* __restrict__ W,
    const float* __restrict__ bias, const float* __restrict__ g,
    const float* __restrict__ beta, float* __restrict__ x,
    unsigned short* __restrict__ xb, const unsigned short* __restrict__ pos16,
    unsigned short* __restrict__ qb, int K)
{
  __shared__ unsigned short As[64][32];      // 2 bufs x 32 rows; reused as red
  __shared__ unsigned short Ws[512][32];     // 2 bufs x 256 rows

  int m0 = blockIdx.x * 32;
  int tid = threadIdx.x;
  int wave = tid >> 6, lane = tid & 63;      // wave 0..7 owns cols [wave*32,+32)
  int lr = lane & 15;
  int lkr = ((lane >> 4) ^ (lane & 3)) * 8;  // swizzled read chunk
  int srow = lane >> 2;
  int schunk = ((lane & 3) ^ (srow & 3)) * 8;

  const unsigned short* Ag = A + (size_t)(m0 + (wave & 1) * 16 + srow) * K + schunk;
  const unsigned short* Wg = W + (size_t)(wave * 32 + srow) * K + schunk;

#define STAGE_LN(k0, buf)                                                      \
  { if (wave < 2) gload16(Ag + (k0), &As[(buf) * 32 + wave * 16][0]);          \
    gload16(Wg + (k0),                  &Ws[(buf) * 256 + wave * 32][0]);      \
    gload16(Wg + (size_t)16 * K + (k0), &Ws[(buf) * 256 + wave * 32 + 16][0]); }

  f32x4 acc[2][2] = {};

  STAGE_LN(0, 0);
  __syncthreads();
  int cur = 0;
  for (int k0 = 0; k0 < K; k0 += 32) {
    if (k0 + 32 < K) STAGE_LN(k0 + 32, cur ^ 1);
    bf16x8 af[2], bfv[2];
#pragma unroll
    for (int m = 0; m < 2; m++)
      af[m] = *(const bf16x8*)&As[cur * 32 + m * 16 + lr][lkr];
#pragma unroll
    for (int n = 0; n < 2; n++)
      bfv[n] = *(const bf16x8*)&Ws[cur * 256 + wave * 32 + n * 16 + lr][lkr];
#pragma unroll
    for (int m = 0; m < 2; m++)
#pragma unroll
      for (int n = 0; n < 2; n++)
        acc[m][n] = __builtin_amdgcn_mfma_f32_16x16x32_bf16(af[m], bfv[n], acc[m][n], 0, 0, 0);
    __syncthreads();
    cur ^= 1;
  }
#undef STAGE_LN

  // v = gemm + bias + residual
#pragma unroll
  for (int n = 0; n < 2; n++) {
    int col = wave * 32 + n * 16 + lr;
    float bv = bias[col];
#pragma unroll
    for (int m = 0; m < 2; m++) {
      int grow = m0 + m * 16 + (lane >> 4) * 4;
#pragma unroll
      for (int j = 0; j < 4; j++)
        acc[m][n][j] += bv + x[(size_t)(grow + j) * DMM + col];
    }
  }

  // per-row (sum, sumsq): 2 n-frags in-reg, 16 lanes shfl, 8 waves via LDS
  float2* red = (float2*)&As[0][0];           // [32 rows][8 waves] = 2 KB
#pragma unroll
  for (int m = 0; m < 2; m++) {
#pragma unroll
    for (int j = 0; j < 4; j++) {
      float s  = acc[m][0][j] + acc[m][1][j];
      float s2 = acc[m][0][j] * acc[m][0][j] + acc[m][1][j] * acc[m][1][j];
#pragma unroll
      for (int o = 1; o < 16; o <<= 1) {
        s  += __shfl_xor(s,  o, 64);
        s2 += __shfl_xor(s2, o, 64);
      }
      if (lr == 0)
        red[(m * 16 + (lane >> 4) * 4 + j) * 8 + wave] = make_float2(s, s2);
    }
  }
  __syncthreads();

#pragma unroll
  for (int m = 0; m < 2; m++) {
#pragma unroll
    for (int j = 0; j < 4; j++) {
      int rl = m * 16 + (lane >> 4) * 4 + j;
      float ts = 0.f, ts2 = 0.f;
#pragma unroll
      for (int wv = 0; wv < 8; wv++) {
        float2 r = red[rl * 8 + wv];
        ts += r.x; ts2 += r.y;
      }
      float mean = ts * (1.0f / DMM);
      float var  = ts2 * (1.0f / DMM) - mean * mean;
      float sc = rsqrtf(var + 1e-5f);
      int grow = m0 + rl;
#pragma unroll
      for (int n = 0; n < 2; n++) {
        int col = wave * 32 + n * 16 + lr;
        float o = (acc[m][n][j] - mean) * sc * g[col] + beta[col];
        size_t idx = (size_t)grow * DMM + col;
        x[idx]  = o;
        xb[idx] = f2b(o);
        if (qb) qb[idx] = f2b(o + b2f(pos16[idx]));
      }
    }
  }
}

// ---------------------------------------------------------------------------
// Deformable sampling. Block = 8 queries x 32 lanes (8 heads x 4 dgroups of 8ch).
// offaw16 is bf16 (B,QTOT,288): off [0..192), aw [192..288).
// ---------------------------------------------------------------------------
__global__ __launch_bounds__(256) void msda_sample(
    const unsigned short* __restrict__ value, const unsigned short* __restrict__ offaw16,
    unsigned short* __restrict__ attn16)
{
  __shared__ float saw[8][96];
  __shared__ float smx[64], sinv[64];
  __shared__ float swgt[768 * 4];   // [p][q][h] x 4 weights
  __shared__ int   sofs[768 * 4];   // [p][q][h] x 4 byte offsets

  int tid = threadIdx.x;
  int qi = tid >> 5, t32 = tid & 31;
  int h = t32 >> 2, dg = t32 & 3;
  int bq0 = blockIdx.x * 8;
  int bq = bq0 + qi;
  int b = bq / QTOT;

  for (int i = t32; i < 96; i += 32)
    saw[qi][i] = b2f(offaw16[(size_t)bq * NOA + 192 + i]);
  __syncthreads();

  if (tid < 64) {
    int q2 = tid >> 3, h2 = tid & 7;
    float mx = -1e30f;
#pragma unroll
    for (int t = 0; t < 12; t++) mx = fmaxf(mx, saw[q2][h2 * 12 + t]);
    float den = 0.f;
#pragma unroll
    for (int t = 0; t < 12; t++) den += __expf(saw[q2][h2 * 12 + t] - mx);
    smx[tid] = mx;
    sinv[tid] = 1.0f / den;
  }
  __syncthreads();

  // phase 2: point-set precompute (s = p*64 + q*8 + h)
  for (int s = tid; s < 768; s += 256) {
    int p = s >> 6;
    int qh = s & 63;
    int q2 = qh >> 3, h2 = qh & 7;
    int l = p >> 2;
    int Wl = 64 >> l;
    int st = (l == 0) ? 0 : ((l == 1) ? 4096 : 5120);

    int q = (bq0 + q2) % QTOT;
    int qq, Wq;
    if (q < 4096)      { qq = q;        Wq = 64; }
    else if (q < 5120) { qq = q - 4096; Wq = 32; }
    else               { qq = q - 5120; Wq = 16; }
    float refx = ((qq % Wq) + 0.5f) / Wq;
    float refy = ((qq / Wq) + 0.5f) / Wq;

    int oi = ((h2 * NLVLS + l) * NPTS + (p & 3)) * 2;
    ushort2 ob = *(const ushort2*)&offaw16[(size_t)(bq0 + q2) * NOA + oi];
    float offx = b2f(ob.x), offy = b2f(ob.y);
    float invW = 1.0f / (float)Wl;
    float xf = (refx + offx * invW) * Wl - 0.5f;
    float yf = (refy + offy * invW) * Wl - 0.5f;
    float x0f = floorf(xf), y0f = floorf(yf);
    float fx = xf - x0f, fy = yf - y0f;
    int x0 = (int)x0f, y0 = (int)y0f;

    float aw = __expf(saw[q2][h2 * 12 + p] - smx[qh]) * sinv[qh];
    float w00 = (1.f - fx) * (1.f - fy) * aw;
    float w10 = fx * (1.f - fy) * aw;
    float w01 = (1.f - fx) * fy * aw;
    float w11 = fx * fy * aw;

    bool xv0 = (x0 >= 0) & (x0 < Wl);
    bool xv1 = (x0 + 1 >= 0) & (x0 + 1 < Wl);
    bool yv0 = (y0 >= 0) & (y0 < Wl);
    bool yv1 = (y0 + 1 >= 0) & (y0 + 1 < Wl);

    int base = s * 4;
    swgt[base + 0] = (xv0 & yv0) ? w00 : 0.f;
    swgt[base + 1] = (xv1 & yv0) ? w10 : 0.f;
    swgt[base + 2] = (xv0 & yv1) ? w01 : 0.f;
    swgt[base + 3] = (xv1 & yv1) ? w11 : 0.f;
    sofs[base + 0] = (xv0 & yv0) ? (st + y0 * Wl + x0) * (DMM * 2) : 0;
    sofs[base + 1] = (xv1 & yv0) ? (st + y0 * Wl + x0 + 1) * (DMM * 2) : 0;
    sofs[base + 2] = (xv0 & yv1) ? (st + (y0 + 1) * Wl + x0) * (DMM * 2) : 0;
    sofs[base + 3] = (xv1 & yv1) ? (st + (y0 + 1) * Wl + x0 + 1) * (DMM * 2) : 0;
  }
  __syncthreads();

  // phase 3: gathers (8 channels per lane)
  float a8[8];
#pragma unroll
  for (int k = 0; k < 8; k++) a8[k] = 0.f;
  const char* vbase = (const char*)(value + (size_t)b * QTOT * DMM + h * HDIM + dg * 8);
#pragma unroll
  for (int p = 0; p < 12; p++) {
    int s3 = (p * 64 + qi * 8 + h) * 4;
    float4 w = *(const float4*)&swgt[s3];
    int4  of = *(const int4*)&sofs[s3];
    u16x8 g0 = *(const u16x8*)(vbase + of.x);
    u16x8 g1 = *(const u16x8*)(vbase + of.y);
    u16x8 g2 = *(const u16x8*)(vbase + of.z);
    u16x8 g3 = *(const u16x8*)(vbase + of.w);
#pragma unroll
    for (int k = 0; k < 8; k++)
      a8[k] += w.x * b2f((unsigned short)g0[k]) + w.y * b2f((unsigned short)g1[k])
             + w.z * b2f((unsigned short)g2[k]) + w.w * b2f((unsigned short)g3[k]);
  }
  u16x8 o;
#pragma unroll
  for (int k = 0; k < 8; k++) o[k] = f2b(a8[k]);
  *(u16x8*)(attn16 + (size_t)bq * DMM + h * HDIM + dg * 8) = o;
}

// ---------------------------------------------------------------------------
extern "C" void kernel_launch(void* const* d_in, const int* in_sizes, int n_in,
                              void* d_out, int out_size, void* d_ws, size_t ws_size,
                              hipStream_t stream)
{
  const float* src[3] = {(const float*)d_in[0], (const float*)d_in[1], (const float*)d_in[2]};
  const float* pin[3] = {(const float*)d_in[3], (const float*)d_in[4], (const float*)d_in[5]};
  const float* lvl_emb = (const float*)d_in[6];
  const float* off_w = (const float*)d_in[7];
  const float* off_b = (const float*)d_in[8];
  const float* aw_w  = (const float*)d_in[9];
  const float* aw_b  = (const float*)d_in[10];
  const float* val_w = (const float*)d_in[11];
  const float* val_b = (const float*)d_in[12];
  const float* out_w = (const float*)d_in[13];
  const float* out_b = (const float*)d_in[14];
  const float* ln1_g = (const float*)d_in[15];
  const float* ln1_b = (const float*)d_in[16];
  const float* ffn1_w = (const float*)d_in[17];
  const float* ffn1_b = (const float*)d_in[18];
  const float* ffn2_w = (const float*)d_in[19];
  const float* ffn2_b = (const float*)d_in[20];
  const float* ln2_g = (const float*)d_in[21];
  const float* ln2_b = (const float*)d_in[22];

  float* x = (float*)d_out;                                  // (B,QTOT,256) f32

  char* wsp = (char*)d_ws;
  unsigned short* offaw16 = (unsigned short*)wsp; wsp += (size_t)BQ * NOA * 2; // 12.4 MB
  unsigned short* valb16  = (unsigned short*)wsp; wsp += (size_t)BQ * 256 * 2; // 11 MB
  unsigned short* attnb   = (unsigned short*)wsp; wsp += (size_t)BQ * 256 * 2; // 11 MB
  unsigned short* hb = offaw16;  // aliased region; pad below so hb's 44 MB fits
  wsp += (size_t)10 * 1024 * 1024;
  unsigned short* pos16 = (unsigned short*)wsp; wsp += (size_t)BQ * 256 * 2;
  unsigned short* xb = (unsigned short*)wsp; wsp += (size_t)BQ * 256 * 2;
  unsigned short* qb = (unsigned short*)wsp; wsp += (size_t)BQ * 256 * 2;

  unsigned short* vWb  = (unsigned short*)wsp; wsp += (size_t)6 * 256 * 256 * 2;
  unsigned short* oaWb = (unsigned short*)wsp; wsp += (size_t)6 * NOA * 256 * 2;
  unsigned short* uWb  = (unsigned short*)wsp; wsp += (size_t)6 * 256 * 256 * 2;
  unsigned short* f1Wb = (unsigned short*)wsp; wsp += (size_t)6 * 1024 * 256 * 2;
  unsigned short* f2Wb = (unsigned short*)wsp; wsp += (size_t)6 * 256 * 1024 * 2;
  float* oaBias = (float*)wsp; wsp += (size_t)6 * NOA * 4;
  wsp += 65536;   // slack for masked-N OOB staging reads

  conv_b<<<(6 * 65536 / 4 + 255) / 256, 256, 0, stream>>>(val_w, vWb, 6 * 65536 / 4);
  conv_b<<<(6 * 65536 / 4 + 255) / 256, 256, 0, stream>>>(out_w, uWb, 6 * 65536 / 4);
  conv_b<<<(6 * 262144 / 4 + 255) / 256, 256, 0, stream>>>(ffn1_w, f1Wb, 6 * 262144 / 4);
  conv_b<<<(6 * 262144 / 4 + 255) / 256, 256, 0, stream>>>(ffn2_w, f2Wb, 6 * 262144 / 4);
  pack_oa<<<(6 * NOA * 64 + 255) / 256, 256, 0, stream>>>(off_w, aw_w, oaWb);
  pack_oa_bias<<<(6 * NOA + 255) / 256, 256, 0, stream>>>(off_b, aw_b, oaBias);

  const int HWs[3] = {4096, 1024, 256};
  const int starts[3] = {0, 4096, 5120};
  for (int l = 0; l < 3; l++) {
    dim3 g(HWs[l] / 32, DMM / 32, BB), blk(32, 8);
    transpose2<<<g, blk, 0, stream>>>(src[l], pin[l], lvl_emb + l * 256,
                                      x, pos16, HWs[l], starts[l]);
  }
  prep<<<(BQ * 256 / 4 + 255) / 256, 256, 0, stream>>>(x, pos16, xb, qb, BQ * 256 / 4);

  for (int i = 0; i < 6; i++) {
    gemm_valoa<<<dim3(BQ / 128, 5), 256, 0, stream>>>(
        xb, qb, vWb + (size_t)i * 65536, oaWb + (size_t)i * NOA * 256,
        val_b + i * 256, oaBias + i * NOA, valb16, offaw16);
    msda_sample<<<BQ / 8, 256, 0, stream>>>(valb16, offaw16, attnb);
    gemm_ln<<<BQ / 32, 512, 0, stream>>>(attnb, uWb + (size_t)i * 65536,
        out_b + i * 256, ln1_g + i * 256, ln1_b + i * 256, x, xb,
        nullptr, nullptr, 256);
    gemm_bf<<<dim3(BQ / 128, 8), 256, 0, stream>>>(xb, f1Wb + (size_t)i * 262144,
        ffn1_b + i * 1024, hb, BQ, 1024, 256, 1 | 2);
    gemm_ln<<<BQ / 32, 512, 0, stream>>>(hb, f2Wb + (size_t)i * 262144,
        ffn2_b + i * 256, ln2_g + i * 256, ln2_b + i * 256, x, xb,
        pos16, qb, 1024);
  }
}